// Round 1
// baseline (488.011 us; speedup 1.0000x reference)
//
#include <hip/hip_runtime.h>
#include <hip/hip_bf16.h>

typedef __attribute__((ext_vector_type(8))) short short8;
typedef __attribute__((ext_vector_type(8))) unsigned short u16x8;
typedef __attribute__((ext_vector_type(4))) float f32x4;

#define HIDDEN 2048
#define NH 16
#define NKV 8
#define HD 128
#define T_SEQ 2048
#define B_SZ 2
#define M_TOK (B_SZ * T_SEQ)         // 4096
#define QSIZE (NH * HD)              // 2048
#define KVSIZE (NKV * HD)            // 1024
#define OUTQKV (QSIZE + 2 * KVSIZE)  // 4096

__device__ __forceinline__ unsigned short f2bf(float f) {
  unsigned int u = __builtin_bit_cast(unsigned int, f);
  u += 0x7FFFu + ((u >> 16) & 1u);   // round-to-nearest-even
  return (unsigned short)(u >> 16);
}
__device__ __forceinline__ float bf2f(unsigned short h) {
  return __builtin_bit_cast(float, (unsigned int)h << 16);
}

// ---------------- GEMM (A[M,K] x B[N,K]^T -> C[M,N]), bf16 MFMA ----------------
#define BM 128
#define BN 128
#define BK 32
#define LDT 40  // padded LDS leading dim (bf16 elems): 80B rows -> no 2^k bank stride

__device__ __forceinline__ void stage16(unsigned short* dst, const float* src) {
  const float4* s = (const float4*)src;
  float4 a = s[0], b = s[1], c = s[2], d = s[3];
  u16x8 lo = {f2bf(a.x), f2bf(a.y), f2bf(a.z), f2bf(a.w),
              f2bf(b.x), f2bf(b.y), f2bf(b.z), f2bf(b.w)};
  u16x8 hi = {f2bf(c.x), f2bf(c.y), f2bf(c.z), f2bf(c.w),
              f2bf(d.x), f2bf(d.y), f2bf(d.z), f2bf(d.w)};
  *(u16x8*)dst = lo;
  *(u16x8*)(dst + 8) = hi;
}
__device__ __forceinline__ void stage16(unsigned short* dst, const unsigned short* src) {
  const u16x8* s = (const u16x8*)src;
  *(u16x8*)dst = s[0];
  *(u16x8*)(dst + 8) = s[1];
}
__device__ __forceinline__ void cstore(float* p, float v) { *p = v; }
__device__ __forceinline__ void cstore(unsigned short* p, float v) { *p = f2bf(v); }

template <typename TA, typename TB, typename TC>
__global__ __launch_bounds__(256) void gemm_bt(const TA* __restrict__ A,
                                               const TB* __restrict__ B,
                                               TC* __restrict__ C,
                                               int M, int N, int K) {
  __shared__ unsigned short lsA[BM * LDT];
  __shared__ unsigned short lsB[BN * LDT];
  const int t = threadIdx.x;
  const int wave = t >> 6, lane = t & 63;
  const int wr = wave >> 1, wc = wave & 1;  // 2x2 waves, 64x64 each
  const int m0 = blockIdx.x * BM, n0 = blockIdx.y * BN;
  const int srow = t >> 1, sseg = (t & 1) * 16;  // staging: 16 elems/thread/tile
  const int lr = lane & 15, lk = (lane >> 4) * 8;
  f32x4 acc[4][4] = {};

  const TA* ag = A + (size_t)(m0 + srow) * K + sseg;
  const TB* bg = B + (size_t)(n0 + srow) * K + sseg;
  unsigned short* la = &lsA[srow * LDT + sseg];
  unsigned short* lb = &lsB[srow * LDT + sseg];

  for (int k0 = 0; k0 < K; k0 += BK) {
    stage16(la, ag + k0);
    stage16(lb, bg + k0);
    __syncthreads();
    short8 af[4], bf[4];
    for (int i = 0; i < 4; i++)
      af[i] = *(const short8*)&lsA[(wr * 64 + i * 16 + lr) * LDT + lk];
    for (int j = 0; j < 4; j++)
      bf[j] = *(const short8*)&lsB[(wc * 64 + j * 16 + lr) * LDT + lk];
    for (int i = 0; i < 4; i++)
      for (int j = 0; j < 4; j++)
        acc[i][j] = __builtin_amdgcn_mfma_f32_16x16x32_bf16(af[i], bf[j], acc[i][j], 0, 0, 0);
    __syncthreads();
  }
  // C/D layout (m89/m91): col = lane&15, row = (lane>>4)*4 + reg
  for (int i = 0; i < 4; i++)
    for (int j = 0; j < 4; j++) {
      int gm = m0 + wr * 64 + i * 16 + (lane >> 4) * 4;
      int gn = n0 + wc * 64 + j * 16 + lr;
      TC* cp = C + (size_t)gm * N + gn;
      for (int r = 0; r < 4; r++) cstore(cp + (size_t)r * N, acc[i][j][r]);
    }
}

// ---------------- per-head RMSNorm + NeoX RoPE + scatter to attn layout ----------------
__global__ void norm_rope_kernel(const unsigned short* __restrict__ qkv,
                                 const int* __restrict__ positions,
                                 const float* __restrict__ rms_w,
                                 unsigned short* __restrict__ qa,
                                 unsigned short* __restrict__ ka,
                                 unsigned short* __restrict__ va) {
  const int m = blockIdx.x;           // token index b*T + t
  const int b = m >> 11, tt = m & 2047;
  const int lane = threadIdx.x;       // 64 lanes; lane d owns pair (d, d+64)
  const float pos = (float)positions[m];
  const float inv_freq = powf(10000.0f, -(float)lane * (1.0f / 64.0f));
  float sv, cv;
  sincosf(pos * inv_freq, &sv, &cv);
  const float w1 = rms_w[lane], w2 = rms_w[lane + 64];
  const unsigned short* src = qkv + (size_t)m * OUTQKV;
  for (int h = 0; h < 32; h++) {      // 16 q heads, 8 k heads, 8 v heads
    unsigned short r1 = src[h * 128 + lane], r2 = src[h * 128 + 64 + lane];
    if (h >= 24) {                    // v: plain copy
      unsigned short* dst = va + (((size_t)b * NKV + (h - 24)) * T_SEQ + tt) * HD;
      dst[lane] = r1; dst[lane + 64] = r2;
      continue;
    }
    float x1 = bf2f(r1), x2 = bf2f(r2);
    float ss = x1 * x1 + x2 * x2;
    ss += __shfl_xor(ss, 1);  ss += __shfl_xor(ss, 2);  ss += __shfl_xor(ss, 4);
    ss += __shfl_xor(ss, 8);  ss += __shfl_xor(ss, 16); ss += __shfl_xor(ss, 32);
    float rstd = rsqrtf(ss * (1.0f / 128.0f) + 1e-6f);
    float y1 = x1 * rstd * w1, y2 = x2 * rstd * w2;
    float o1 = y1 * cv - y2 * sv, o2 = y2 * cv + y1 * sv;
    unsigned short* dst;
    if (h < 16) dst = qa + (((size_t)b * NH + h) * T_SEQ + tt) * HD;
    else        dst = ka + (((size_t)b * NKV + (h - 16)) * T_SEQ + tt) * HD;
    dst[lane] = f2bf(o1); dst[lane + 64] = f2bf(o2);
  }
}

// ---------------- flash attention (causal, GQA g=2) ----------------
#define QB 64
#define KB 64
#define LDQK 136  // 272B rows -> ~2-way max on b128 reads
#define LDV 72    // V^T tile rows (64 kv + pad)

__global__ __launch_bounds__(256) void attn_kernel(const unsigned short* __restrict__ qa,
                                                   const unsigned short* __restrict__ ka,
                                                   const unsigned short* __restrict__ va,
                                                   unsigned short* __restrict__ ob) {
  __shared__ unsigned short qs[QB * LDQK];
  __shared__ unsigned short ks[KB * LDQK];
  __shared__ unsigned short vt[HD * LDV];   // transposed: vt[d][kk]
  __shared__ unsigned short ps[4][16 * 72]; // per-wave P tile

  const int qt = blockIdx.x, h = blockIdx.y, b = blockIdx.z;
  const int kvh = h >> 1;
  const int t = threadIdx.x, wave = t >> 6, lane = t & 63;
  const int lr = lane & 15, lk = (lane >> 4) * 8, lrow = (lane >> 4) * 4;

  const unsigned short* Qg = qa + (((size_t)b * NH + h) * T_SEQ + qt * QB) * HD;
  const unsigned short* Kg = ka + ((size_t)b * NKV + kvh) * T_SEQ * HD;
  const unsigned short* Vg = va + ((size_t)b * NKV + kvh) * T_SEQ * HD;

  const int sr = t & 63, sd = (t >> 6) * 32;  // staging: row sr, 32 d-cols
  {
    const u16x8* s = (const u16x8*)(Qg + sr * HD + sd);
    for (int i = 0; i < 4; i++) *(u16x8*)&qs[sr * LDQK + sd + i * 8] = s[i];
  }
  f32x4 oacc[8] = {};
  float mrow[4] = {-1e30f, -1e30f, -1e30f, -1e30f};
  float lsum[4] = {};
  const float scale = 0.08838834764831845f;  // 1/sqrt(128)

  for (int j = 0; j <= qt; j++) {
    __syncthreads();  // prev iteration done reading ks/vt (and Q visible on iter 0 via next sync)
    {
      const u16x8* sK = (const u16x8*)(Kg + (size_t)(j * KB + sr) * HD + sd);
      for (int i = 0; i < 4; i++) *(u16x8*)&ks[sr * LDQK + sd + i * 8] = sK[i];
      const u16x8* sV = (const u16x8*)(Vg + (size_t)(j * KB + sr) * HD + sd);
      u16x8 vv[4];
      for (int i = 0; i < 4; i++) vv[i] = sV[i];
      for (int i = 0; i < 4; i++)
        for (int e = 0; e < 8; e++)
          vt[(sd + i * 8 + e) * LDV + sr] = vv[i][e];
    }
    __syncthreads();
    // S = Q K^T : wave owns S rows [wave*16, wave*16+16) x 64 cols
    f32x4 sacc[4] = {};
    short8 aq[4];
    for (int kk = 0; kk < 4; kk++)
      aq[kk] = *(const short8*)&qs[(wave * 16 + lr) * LDQK + kk * 32 + lk];
    for (int jf = 0; jf < 4; jf++)
      for (int kk = 0; kk < 4; kk++) {
        short8 bk = *(const short8*)&ks[(jf * 16 + lr) * LDQK + kk * 32 + lk];
        sacc[jf] = __builtin_amdgcn_mfma_f32_16x16x32_bf16(aq[kk], bk, sacc[jf], 0, 0, 0);
      }
    // causal mask + online softmax (rows live in 16-lane groups, 4 regs)
    float pv[4][4];
    const int rbase = qt * QB + wave * 16 + lrow;
    const int cbase = j * KB + lr;
    for (int r = 0; r < 4; r++) {
      float sv4[4], vmax = -1e30f;
      for (int jf = 0; jf < 4; jf++) {
        float s = sacc[jf][r] * scale;
        if (cbase + jf * 16 > rbase + r) s = -1e30f;
        sv4[jf] = s;
        vmax = fmaxf(vmax, s);
      }
      vmax = fmaxf(vmax, __shfl_xor(vmax, 1));
      vmax = fmaxf(vmax, __shfl_xor(vmax, 2));
      vmax = fmaxf(vmax, __shfl_xor(vmax, 4));
      vmax = fmaxf(vmax, __shfl_xor(vmax, 8));
      float mnew = fmaxf(mrow[r], vmax);
      float corr = __expf(mrow[r] - mnew);
      mrow[r] = mnew;
      float psum = 0.f;
      for (int jf = 0; jf < 4; jf++) {
        float p = __expf(sv4[jf] - mnew);
        pv[jf][r] = p;
        psum += p;
      }
      psum += __shfl_xor(psum, 1); psum += __shfl_xor(psum, 2);
      psum += __shfl_xor(psum, 4); psum += __shfl_xor(psum, 8);
      lsum[r] = lsum[r] * corr + psum;
      for (int dt = 0; dt < 8; dt++) oacc[dt][r] *= corr;
    }
    // P -> LDS (wave-private; same-wave ds_write->ds_read ordered by lgkmcnt)
    for (int jf = 0; jf < 4; jf++)
      for (int r = 0; r < 4; r++)
        ps[wave][(lrow + r) * 72 + jf * 16 + lr] = f2bf(pv[jf][r]);
    // O += P V
    short8 pf0 = *(const short8*)&ps[wave][lr * 72 + lk];
    short8 pf1 = *(const short8*)&ps[wave][lr * 72 + 32 + lk];
    for (int dt = 0; dt < 8; dt++) {
      short8 bv0 = *(const short8*)&vt[(dt * 16 + lr) * LDV + lk];
      short8 bv1 = *(const short8*)&vt[(dt * 16 + lr) * LDV + 32 + lk];
      oacc[dt] = __builtin_amdgcn_mfma_f32_16x16x32_bf16(pf0, bv0, oacc[dt], 0, 0, 0);
      oacc[dt] = __builtin_amdgcn_mfma_f32_16x16x32_bf16(pf1, bv1, oacc[dt], 0, 0, 0);
    }
  }
  // epilogue: normalize and scatter to [B*T][NH*HD]
  for (int r = 0; r < 4; r++) {
    float inv = 1.0f / lsum[r];
    int row_t = qt * QB + wave * 16 + lrow + r;
    unsigned short* dst = ob + ((size_t)b * T_SEQ + row_t) * QSIZE + h * HD;
    for (int dt = 0; dt < 8; dt++)
      dst[dt * 16 + lr] = f2bf(oacc[dt][r] * inv);
  }
}

// ---------------- launch ----------------
extern "C" void kernel_launch(void* const* d_in, const int* in_sizes, int n_in,
                              void* d_out, int out_size, void* d_ws, size_t ws_size,
                              hipStream_t stream) {
  const int* positions = (const int*)d_in[0];
  const float* hidden  = (const float*)d_in[1];
  const float* w_qkv   = (const float*)d_in[2];
  const float* w_o     = (const float*)d_in[3];
  const float* rms_w   = (const float*)d_in[4];
  float* out = (float*)d_out;

  unsigned short* qkv = (unsigned short*)d_ws;               // [4096][4096] bf16
  unsigned short* qa  = qkv + (size_t)M_TOK * OUTQKV;        // [2][16][2048][128]
  unsigned short* ka  = qa + (size_t)B_SZ * NH * T_SEQ * HD; // [2][8][2048][128]
  unsigned short* va  = ka + (size_t)B_SZ * NKV * T_SEQ * HD;
  unsigned short* ob  = qkv;  // alias: qkv dead after norm_rope

  gemm_bt<float, float, unsigned short>
      <<<dim3(M_TOK / BM, OUTQKV / BN), 256, 0, stream>>>(hidden, w_qkv, qkv, M_TOK, OUTQKV, HIDDEN);
  norm_rope_kernel<<<M_TOK, 64, 0, stream>>>(qkv, positions, rms_w, qa, ka, va);
  attn_kernel<<<dim3(T_SEQ / QB, NH, B_SZ), 256, 0, stream>>>(qa, ka, va, ob);
  gemm_bt<unsigned short, float, float>
      <<<dim3(M_TOK / BM, HIDDEN / BN), 256, 0, stream>>>(ob, w_o, out, M_TOK, HIDDEN, HIDDEN);
}

// Round 2
// 329.961 us; speedup vs baseline: 1.4790x; 1.4790x over previous
//
#include <hip/hip_runtime.h>
#include <hip/hip_bf16.h>

typedef __attribute__((ext_vector_type(8))) short short8;
typedef __attribute__((ext_vector_type(8))) unsigned short u16x8;
typedef __attribute__((ext_vector_type(4))) float f32x4;

#define HIDDEN 2048
#define NH 16
#define NKV 8
#define HD 128
#define T_SEQ 2048
#define B_SZ 2
#define M_TOK (B_SZ * T_SEQ)         // 4096
#define QSIZE (NH * HD)              // 2048
#define KVSIZE (NKV * HD)            // 1024
#define OUTQKV (QSIZE + 2 * KVSIZE)  // 4096

__device__ __forceinline__ unsigned short f2bf(float f) {
  unsigned int u = __builtin_bit_cast(unsigned int, f);
  u += 0x7FFFu + ((u >> 16) & 1u);   // round-to-nearest-even
  return (unsigned short)(u >> 16);
}
__device__ __forceinline__ float bf2f(unsigned short h) {
  return __builtin_bit_cast(float, (unsigned int)h << 16);
}

typedef __attribute__((address_space(3))) void lds_void;
typedef __attribute__((address_space(1))) const void glb_void;
__device__ __forceinline__ void gld16(const void* g, void* l) {
  __builtin_amdgcn_global_load_lds((glb_void*)g, (lds_void*)l, 16, 0, 0);
}

__device__ __forceinline__ void cstore(float* p, float v) { *p = v; }
__device__ __forceinline__ void cstore(unsigned short* p, float v) { *p = f2bf(v); }

// ---------------- f32 -> bf16 convert ----------------
__global__ void cvt_f32_bf16(const float* __restrict__ in, unsigned short* __restrict__ out, int n8) {
  int i = blockIdx.x * blockDim.x + threadIdx.x;
  if (i >= n8) return;
  const float4* p = (const float4*)in + (size_t)i * 2;
  float4 a = p[0], b = p[1];
  u16x8 o = {f2bf(a.x), f2bf(a.y), f2bf(a.z), f2bf(a.w),
             f2bf(b.x), f2bf(b.y), f2bf(b.z), f2bf(b.w)};
  ((u16x8*)out)[i] = o;
}

// ---------------- GEMM: C[M,N] = A[M,K] * B[N,K]^T, bf16 MFMA ----------------
// GLDx: operand is bf16, staged via global_load_lds (linear LDS, wave-chunked).
// !GLDx: operand is f32, reg-staged (issue-early / convert+write-late, T14).
template <bool GLDA, bool GLDB, typename TA, typename TB, typename TC>
__global__ __launch_bounds__(256) void gemm_k(const TA* __restrict__ A,
                                              const TB* __restrict__ B,
                                              TC* __restrict__ C,
                                              int M, int N, int K) {
  __shared__ unsigned short lsA[2][128 * 32];
  __shared__ unsigned short lsB[2][128 * 32];
  const int t = threadIdx.x;
  const int wave = t >> 6, lane = t & 63;
  const int wr = wave >> 1, wc = wave & 1;
  const int m0 = blockIdx.x * 128, n0 = blockIdx.y * 128;
  const int lr = lane & 15, lk = (lane >> 4) * 8;
  // reg-staging mapping (f32): rows srow & srow+64, 8-elem segment
  const int srow = t >> 2;
  const int sseg = (t & 3) * 8;
  // gld_lds mapping: wave chunk i covers rows wave*32+i*16..+16
  const int gsub = lane >> 2;
  const int gcol = (lane & 3) * 8;

  f32x4 acc[4][4] = {};
  const int nt = K >> 5;
  float4 ra[4], rb[4];

  auto issueA = [&](int k0, int buf) {
    if constexpr (GLDA) {
#pragma unroll
      for (int i = 0; i < 2; i++) {
        const unsigned short* g = (const unsigned short*)A +
            (size_t)(m0 + wave * 32 + i * 16 + gsub) * K + k0 + gcol;
        gld16(g, &lsA[buf][(wave * 2 + i) * 512]);
      }
    } else {
      const float* ap = (const float*)A + (size_t)(m0 + srow) * K + k0 + sseg;
      ra[0] = *(const float4*)ap; ra[1] = *(const float4*)(ap + 4);
      ap += (size_t)64 * K;
      ra[2] = *(const float4*)ap; ra[3] = *(const float4*)(ap + 4);
    }
  };
  auto issueB = [&](int k0, int buf) {
    if constexpr (GLDB) {
#pragma unroll
      for (int i = 0; i < 2; i++) {
        const unsigned short* g = (const unsigned short*)B +
            (size_t)(n0 + wave * 32 + i * 16 + gsub) * K + k0 + gcol;
        gld16(g, &lsB[buf][(wave * 2 + i) * 512]);
      }
    } else {
      const float* bp = (const float*)B + (size_t)(n0 + srow) * K + k0 + sseg;
      rb[0] = *(const float4*)bp; rb[1] = *(const float4*)(bp + 4);
      bp += (size_t)64 * K;
      rb[2] = *(const float4*)bp; rb[3] = *(const float4*)(bp + 4);
    }
  };
  auto writeA = [&](int buf) {
    if constexpr (!GLDA) {
      u16x8 w0 = {f2bf(ra[0].x), f2bf(ra[0].y), f2bf(ra[0].z), f2bf(ra[0].w),
                  f2bf(ra[1].x), f2bf(ra[1].y), f2bf(ra[1].z), f2bf(ra[1].w)};
      u16x8 w1 = {f2bf(ra[2].x), f2bf(ra[2].y), f2bf(ra[2].z), f2bf(ra[2].w),
                  f2bf(ra[3].x), f2bf(ra[3].y), f2bf(ra[3].z), f2bf(ra[3].w)};
      *(u16x8*)&lsA[buf][srow * 32 + sseg] = w0;
      *(u16x8*)&lsA[buf][(64 + srow) * 32 + sseg] = w1;
    }
  };
  auto writeB = [&](int buf) {
    if constexpr (!GLDB) {
      u16x8 w0 = {f2bf(rb[0].x), f2bf(rb[0].y), f2bf(rb[0].z), f2bf(rb[0].w),
                  f2bf(rb[1].x), f2bf(rb[1].y), f2bf(rb[1].z), f2bf(rb[1].w)};
      u16x8 w1 = {f2bf(rb[2].x), f2bf(rb[2].y), f2bf(rb[2].z), f2bf(rb[2].w),
                  f2bf(rb[3].x), f2bf(rb[3].y), f2bf(rb[3].z), f2bf(rb[3].w)};
      *(u16x8*)&lsB[buf][srow * 32 + sseg] = w0;
      *(u16x8*)&lsB[buf][(64 + srow) * 32 + sseg] = w1;
    }
  };

  // prologue: stage tile 0 into buf 0
  issueA(0, 0); issueB(0, 0); writeA(0); writeB(0);
  asm volatile("s_waitcnt vmcnt(0)" ::: "memory");
  __syncthreads();

  for (int ti = 0; ti < nt; ti++) {
    const int cur = ti & 1, nxt = cur ^ 1;
    const bool more = (ti + 1 < nt);
    if (more) { issueA((ti + 1) << 5, nxt); issueB((ti + 1) << 5, nxt); }
    short8 af[4], bfr[4];
#pragma unroll
    for (int i = 0; i < 4; i++)
      af[i] = *(const short8*)&lsA[cur][(wr * 64 + i * 16 + lr) * 32 + lk];
#pragma unroll
    for (int j = 0; j < 4; j++)
      bfr[j] = *(const short8*)&lsB[cur][(wc * 64 + j * 16 + lr) * 32 + lk];
#pragma unroll
    for (int i = 0; i < 4; i++)
#pragma unroll
      for (int j = 0; j < 4; j++)
        acc[i][j] = __builtin_amdgcn_mfma_f32_16x16x32_bf16(af[i], bfr[j], acc[i][j], 0, 0, 0);
    if (more) { writeA(nxt); writeB(nxt); }
    asm volatile("s_waitcnt vmcnt(0)" ::: "memory");
    __syncthreads();
  }
  // C/D layout: col = lane&15, row = (lane>>4)*4 + reg
#pragma unroll
  for (int i = 0; i < 4; i++)
#pragma unroll
    for (int j = 0; j < 4; j++) {
      int gm = m0 + wr * 64 + i * 16 + (lane >> 4) * 4;
      int gn = n0 + wc * 64 + j * 16 + lr;
      TC* cp = C + (size_t)gm * N + gn;
#pragma unroll
      for (int r = 0; r < 4; r++) cstore(cp + (size_t)r * N, acc[i][j][r]);
    }
}

// ---------------- per-head RMSNorm + NeoX RoPE (q,k only) ----------------
__global__ void norm_rope_kernel(const unsigned short* __restrict__ qkv,
                                 const int* __restrict__ positions,
                                 const float* __restrict__ rms_w,
                                 unsigned short* __restrict__ qa,
                                 unsigned short* __restrict__ ka) {
  const int m = blockIdx.x;           // token index b*T + t
  const int b = m >> 11, tt = m & 2047;
  const int lane = threadIdx.x;       // 64 lanes; lane d owns pair (d, d+64)
  const float pos = (float)positions[m];
  const float inv_freq = powf(10000.0f, -(float)lane * (1.0f / 64.0f));
  float sv, cv;
  sincosf(pos * inv_freq, &sv, &cv);
  const float w1 = rms_w[lane], w2 = rms_w[lane + 64];
  const unsigned short* src = qkv + (size_t)m * OUTQKV;
  for (int h = 0; h < 24; h++) {      // 16 q heads + 8 k heads
    unsigned short r1 = src[h * 128 + lane], r2 = src[h * 128 + 64 + lane];
    float x1 = bf2f(r1), x2 = bf2f(r2);
    float ss = x1 * x1 + x2 * x2;
    ss += __shfl_xor(ss, 1);  ss += __shfl_xor(ss, 2);  ss += __shfl_xor(ss, 4);
    ss += __shfl_xor(ss, 8);  ss += __shfl_xor(ss, 16); ss += __shfl_xor(ss, 32);
    float rstd = rsqrtf(ss * (1.0f / 128.0f) + 1e-6f);
    float y1 = x1 * rstd * w1, y2 = x2 * rstd * w2;
    float o1 = y1 * cv - y2 * sv, o2 = y2 * cv + y1 * sv;
    unsigned short* dst;
    if (h < 16) dst = qa + (((size_t)b * NH + h) * T_SEQ + tt) * HD;
    else        dst = ka + (((size_t)b * NKV + (h - 16)) * T_SEQ + tt) * HD;
    dst[lane] = f2bf(o1); dst[lane + 64] = f2bf(o2);
  }
}

// ---------------- V transpose: qkv v-section -> vat[b][kvh][d][T] ----------------
__global__ __launch_bounds__(256) void v_transpose(const unsigned short* __restrict__ qkv,
                                                   unsigned short* __restrict__ vat) {
  __shared__ unsigned short tile[64][136];
  const int tt0 = blockIdx.x * 64;
  const int kvh = blockIdx.y, b = blockIdx.z;
  const int t = threadIdx.x;
  {
    const int tok = t >> 2, d0 = (t & 3) * 32;
    const unsigned short* src = qkv + (size_t)((size_t)b * T_SEQ + tt0 + tok) * OUTQKV
                                + QSIZE + KVSIZE + kvh * HD + d0;
#pragma unroll
    for (int i = 0; i < 4; i++)
      *(u16x8*)&tile[tok][d0 + i * 8] = *(const u16x8*)(src + i * 8);
  }
  __syncthreads();
  {
    const int d = t >> 1, c0 = (t & 1) * 32;
    unsigned short* dst = vat + ((size_t)((size_t)b * NKV + kvh) * HD + d) * T_SEQ + tt0 + c0;
#pragma unroll
    for (int j = 0; j < 4; j++) {
      u16x8 v;
#pragma unroll
      for (int e = 0; e < 8; e++) v[e] = tile[c0 + j * 8 + e][d];
      *(u16x8*)(dst + j * 8) = v;
    }
  }
}

// ---------------- flash attention (causal, GQA paired: 2 q-heads/block) ----------------
// grid: 512 blocks, LPT order (descending qt). block = 512 threads = 8 waves.
// wave w: head kvh*2 + (w>>2), q-rows qt*64 + (w&3)*16 .. +16.
__global__ __launch_bounds__(512, 4) void attn_kernel(const unsigned short* __restrict__ qa,
                                                      const unsigned short* __restrict__ ka,
                                                      const unsigned short* __restrict__ vat,
                                                      unsigned short* __restrict__ ob) {
  __shared__ unsigned short ks[64 * 136];
  __shared__ unsigned short vt[128 * 72];
  __shared__ unsigned short ps[8][16 * 72];

  const int bx = blockIdx.x;
  const int qt = 31 - (bx >> 4);          // heavy blocks dispatched first (LPT)
  const int kvh = bx & 7, b = (bx >> 3) & 1;
  const int t = threadIdx.x, w = t >> 6, lane = t & 63;
  const int lr = lane & 15, lk = (lane >> 4) * 8, lrow = (lane >> 4) * 4;
  const int h = kvh * 2 + (w >> 2);
  const int rq = (w & 3) * 16;

  const unsigned short* Kg = ka + ((size_t)b * NKV + kvh) * T_SEQ * HD;
  const unsigned short* Vg = vat + ((size_t)b * NKV + kvh) * (size_t)HD * T_SEQ;

  const int krow = t >> 3, kd0 = (t & 7) * 16;  // K staging: 64 rows x 128 d
  const int vd = t >> 2, vk0 = (t & 3) * 16;    // V^T staging: 128 d x 64 k

  // Q fragments in registers (constant over the j loop)
  short8 qf[4];
  const unsigned short* Qg = qa + (((size_t)b * NH + h) * T_SEQ + qt * 64 + rq + lr) * HD;
#pragma unroll
  for (int kk = 0; kk < 4; kk++) qf[kk] = *(const short8*)(Qg + kk * 32 + lk);

  // prologue: stage K/V tile 0
  {
    const u16x8* kp = (const u16x8*)(Kg + (size_t)krow * HD + kd0);
    u16x8 k0v = kp[0], k1v = kp[1];
    const u16x8* vp = (const u16x8*)(Vg + (size_t)vd * T_SEQ + vk0);
    u16x8 v0v = vp[0], v1v = vp[1];
    *(u16x8*)&ks[krow * 136 + kd0] = k0v;
    *(u16x8*)&ks[krow * 136 + kd0 + 8] = k1v;
    *(u16x8*)&vt[vd * 72 + vk0] = v0v;
    *(u16x8*)&vt[vd * 72 + vk0 + 8] = v1v;
  }
  __syncthreads();

  f32x4 oacc[8] = {};
  float mrow[4] = {-1e30f, -1e30f, -1e30f, -1e30f};
  float lsum[4] = {0.f, 0.f, 0.f, 0.f};
  const float scale = 0.08838834764831845f;  // 1/sqrt(128)

  for (int j = 0; j <= qt; j++) {
    const bool more = (j < qt);
    u16x8 kr0, kr1, vr0, vr1;
    if (more) {  // T14: issue next-tile loads early; write after barrier
      const u16x8* kp = (const u16x8*)(Kg + (size_t)((j + 1) * 64 + krow) * HD + kd0);
      kr0 = kp[0]; kr1 = kp[1];
      const u16x8* vp = (const u16x8*)(Vg + (size_t)vd * T_SEQ + (j + 1) * 64 + vk0);
      vr0 = vp[0]; vr1 = vp[1];
    }
    // S = Q K^T : wave tile 16 rows x 64 k-cols
    f32x4 sacc[4] = {};
    __builtin_amdgcn_s_setprio(1);
#pragma unroll
    for (int jf = 0; jf < 4; jf++)
#pragma unroll
      for (int kk = 0; kk < 4; kk++) {
        short8 bk = *(const short8*)&ks[(jf * 16 + lr) * 136 + kk * 32 + lk];
        sacc[jf] = __builtin_amdgcn_mfma_f32_16x16x32_bf16(qf[kk], bk, sacc[jf], 0, 0, 0);
      }
    __builtin_amdgcn_s_setprio(0);
    // causal mask + online softmax; P written straight to per-wave LDS
    const int rbase = qt * 64 + rq + lrow;
    const int cbase = j * 64 + lr;
#pragma unroll
    for (int r = 0; r < 4; r++) {
      float sv4[4], vmax = -1e30f;
#pragma unroll
      for (int jf = 0; jf < 4; jf++) {
        float s = sacc[jf][r] * scale;
        if (cbase + jf * 16 > rbase + r) s = -1e30f;
        sv4[jf] = s;
        vmax = fmaxf(vmax, s);
      }
      vmax = fmaxf(vmax, __shfl_xor(vmax, 1));
      vmax = fmaxf(vmax, __shfl_xor(vmax, 2));
      vmax = fmaxf(vmax, __shfl_xor(vmax, 4));
      vmax = fmaxf(vmax, __shfl_xor(vmax, 8));
      float mnew = fmaxf(mrow[r], vmax);
      float corr = __expf(mrow[r] - mnew);
      mrow[r] = mnew;
      float psum = 0.f;
#pragma unroll
      for (int jf = 0; jf < 4; jf++) {
        float p = __expf(sv4[jf] - mnew);
        psum += p;
        ps[w][(lrow + r) * 72 + jf * 16 + lr] = f2bf(p);
      }
      psum += __shfl_xor(psum, 1); psum += __shfl_xor(psum, 2);
      psum += __shfl_xor(psum, 4); psum += __shfl_xor(psum, 8);
      lsum[r] = lsum[r] * corr + psum;
#pragma unroll
      for (int dt = 0; dt < 8; dt++) oacc[dt][r] *= corr;
    }
    // O += P V  (P from wave-private LDS; same-wave ordering via lgkmcnt)
    short8 pf0 = *(const short8*)&ps[w][lr * 72 + lk];
    short8 pf1 = *(const short8*)&ps[w][lr * 72 + 32 + lk];
    __builtin_amdgcn_s_setprio(1);
#pragma unroll
    for (int dt = 0; dt < 8; dt++) {
      short8 bv0 = *(const short8*)&vt[(dt * 16 + lr) * 72 + lk];
      short8 bv1 = *(const short8*)&vt[(dt * 16 + lr) * 72 + 32 + lk];
      oacc[dt] = __builtin_amdgcn_mfma_f32_16x16x32_bf16(pf0, bv0, oacc[dt], 0, 0, 0);
      oacc[dt] = __builtin_amdgcn_mfma_f32_16x16x32_bf16(pf1, bv1, oacc[dt], 0, 0, 0);
    }
    __builtin_amdgcn_s_setprio(0);
    __syncthreads();  // all waves done reading ks/vt
    if (more) {
      *(u16x8*)&ks[krow * 136 + kd0] = kr0;
      *(u16x8*)&ks[krow * 136 + kd0 + 8] = kr1;
      *(u16x8*)&vt[vd * 72 + vk0] = vr0;
      *(u16x8*)&vt[vd * 72 + vk0 + 8] = vr1;
      __syncthreads();  // uniform branch: j,qt are block-uniform
    }
  }
  // epilogue: normalize, write [B*T][NH*HD] bf16
#pragma unroll
  for (int r = 0; r < 4; r++) {
    float inv = 1.0f / lsum[r];
    int row = qt * 64 + rq + lrow + r;
    unsigned short* dst = ob + ((size_t)b * T_SEQ + row) * QSIZE + h * HD;
#pragma unroll
    for (int dt = 0; dt < 8; dt++)
      dst[dt * 16 + lr] = f2bf(oacc[dt][r] * inv);
  }
}

// ---------------- launch ----------------
extern "C" void kernel_launch(void* const* d_in, const int* in_sizes, int n_in,
                              void* d_out, int out_size, void* d_ws, size_t ws_size,
                              hipStream_t stream) {
  const int* positions = (const int*)d_in[0];
  const float* hidden  = (const float*)d_in[1];
  const float* w_qkv   = (const float*)d_in[2];
  const float* w_o     = (const float*)d_in[3];
  const float* rms_w   = (const float*)d_in[4];
  float* out = (float*)d_out;

  unsigned short* qkv   = (unsigned short*)d_ws;                  // [4096][4096] bf16
  unsigned short* wqkvb = qkv + (size_t)M_TOK * OUTQKV;           // [4096][2048] bf16
  unsigned short* qa    = wqkvb;                                  // alias (wqkvb dead after gemm1)
  unsigned short* ka    = wqkvb + (size_t)OUTQKV * HIDDEN;        // [2][8][2048][128]
  unsigned short* vat   = ka + (size_t)B_SZ * NKV * T_SEQ * HD;   // [2][8][128][2048]
  unsigned short* ob    = qkv;                                    // alias (qkv dead after v_transpose)

  cvt_f32_bf16<<<(OUTQKV * HIDDEN / 8 + 255) / 256, 256, 0, stream>>>(w_qkv, wqkvb, OUTQKV * HIDDEN / 8);
  gemm_k<false, true, float, unsigned short, unsigned short>
      <<<dim3(M_TOK / 128, OUTQKV / 128), 256, 0, stream>>>(hidden, wqkvb, qkv, M_TOK, OUTQKV, HIDDEN);
  norm_rope_kernel<<<M_TOK, 64, 0, stream>>>(qkv, positions, rms_w, qa, ka);
  v_transpose<<<dim3(T_SEQ / 64, NKV, B_SZ), 256, 0, stream>>>(qkv, vat);
  attn_kernel<<<512, 512, 0, stream>>>(qa, ka, vat, ob);
  gemm_k<true, false, unsigned short, float, float>
      <<<dim3(M_TOK / 128, HIDDEN / 128), 256, 0, stream>>>(ob, w_o, out, M_TOK, HIDDEN, QSIZE);
}

// Round 3
// 284.155 us; speedup vs baseline: 1.7174x; 1.1612x over previous
//
#include <hip/hip_runtime.h>
#include <hip/hip_bf16.h>

typedef __attribute__((ext_vector_type(8))) short short8;
typedef __attribute__((ext_vector_type(8))) unsigned short u16x8;
typedef __attribute__((ext_vector_type(4))) float f32x4;

#define HIDDEN 2048
#define NH 16
#define NKV 8
#define HD 128
#define T_SEQ 2048
#define B_SZ 2
#define M_TOK (B_SZ * T_SEQ)         // 4096
#define QSIZE (NH * HD)              // 2048
#define KVSIZE (NKV * HD)            // 1024
#define OUTQKV (QSIZE + 2 * KVSIZE)  // 4096

__device__ __forceinline__ unsigned short f2bf(float f) {
  unsigned int u = __builtin_bit_cast(unsigned int, f);
  u += 0x7FFFu + ((u >> 16) & 1u);   // round-to-nearest-even
  return (unsigned short)(u >> 16);
}
__device__ __forceinline__ float bf2f(unsigned short h) {
  return __builtin_bit_cast(float, (unsigned int)h << 16);
}

typedef __attribute__((address_space(3))) void lds_void;
typedef __attribute__((address_space(1))) const void glb_void;
__device__ __forceinline__ void gld16(const void* g, void* l) {
  __builtin_amdgcn_global_load_lds((glb_void*)g, (lds_void*)l, 16, 0, 0);
}

__device__ __forceinline__ void cstore(float* p, float v) { *p = v; }
__device__ __forceinline__ void cstore(unsigned short* p, float v) { *p = f2bf(v); }

// ---------------- f32 -> bf16 convert ----------------
__global__ void cvt_f32_bf16(const float* __restrict__ in, unsigned short* __restrict__ out, int n8) {
  int i = blockIdx.x * blockDim.x + threadIdx.x;
  if (i >= n8) return;
  const float4* p = (const float4*)in + (size_t)i * 2;
  float4 a = p[0], b = p[1];
  u16x8 o = {f2bf(a.x), f2bf(a.y), f2bf(a.z), f2bf(a.w),
             f2bf(b.x), f2bf(b.y), f2bf(b.z), f2bf(b.w)};
  ((u16x8*)out)[i] = o;
}

// ---------------- 256x256 8-phase GEMM: C[M,N] = A[M,K] x B[N,K]^T (bf16 in) ----------------
// K-half-tile (256 rows x 32 cols) ring of 4 slots per operand; 1 half staged per phase via
// global_load_lds (linear dest, pre-swizzled source); counted vmcnt(4) at phase 2/4 boundaries.
// Swizzle involution: col_byte ^= ((row>>1)&3)<<4 within each 64B row.
template <typename TC>
__global__ __launch_bounds__(512, 2) void gemm8(const unsigned short* __restrict__ A,
                                                const unsigned short* __restrict__ B,
                                                TC* __restrict__ C,
                                                int M, int N, int K) {
  __shared__ unsigned short lsA[4][8192];
  __shared__ unsigned short lsB[4][8192];
  const int tid = threadIdx.x;
  const int wave = tid >> 6, lane = tid & 63;
  const int wr = wave >> 2, wc = wave & 3;       // 2 x 4 waves, each 128x64 of C
  const int lr = lane & 15;
  const int ntn = N >> 8;
  // bijective XCD swizzle (gridDim.x % 8 == 0)
  const int cpx = gridDim.x >> 3;
  const int wg = (blockIdx.x & 7) * cpx + (blockIdx.x >> 3);
  const int m0 = (wg / ntn) * 256, n0 = (wg % ntn) * 256;
  // ds_read column (physical, elements): logical (lane>>4)*8 XOR swizzle((row>>1)&3 == (lr>>1)&3)
  const int ce = 8 * ((lane >> 4) ^ ((lr >> 1) & 3));
  // staging: thread covers rows (tid>>2) and (tid>>2)+128, 16B each; source pre-swizzled
  const int rr0 = tid >> 2;
  const int cle = 8 * ((tid & 3) ^ ((rr0 >> 1) & 3));  // logical source col (elements)
  const unsigned short* pA0 = A + (size_t)(m0 + rr0) * K + cle;
  const unsigned short* pA1 = pA0 + (size_t)128 * K;
  const unsigned short* pB0 = B + (size_t)(n0 + rr0) * K + cle;
  const unsigned short* pB1 = pB0 + (size_t)128 * K;
  const int dst0 = 8 * tid, dst1 = 4096 + 8 * tid;   // linear LDS dest (elements)

  auto stageA = [&](int hn) {
    const int s = hn & 3;
    gld16(pA0 + hn * 32, &lsA[s][dst0]);
    gld16(pA1 + hn * 32, &lsA[s][dst1]);
  };
  auto stageB = [&](int hn) {
    const int s = hn & 3;
    gld16(pB0 + hn * 32, &lsB[s][dst0]);
    gld16(pB1 + hn * 32, &lsB[s][dst1]);
  };

  f32x4 acc[8][4] = {};
  short8 af[4], bfg[4];
  const int NT = K >> 6;  // 64-wide K-tiles; NT >= 2

  // prologue: tile 0 (K-halves 0,1)
  stageA(0); stageB(0); stageA(1); stageB(1);
  asm volatile("s_waitcnt vmcnt(0)" ::: "memory");
  __syncthreads();

#define PHASE(KK, MH, STG, VM)                                                        \
  {                                                                                   \
    const int slot = sb + (KK);                                                       \
    _Pragma("unroll")                                                                 \
    for (int i = 0; i < 4; i++)                                                       \
      af[i] = *(const short8*)&lsA[slot][(wr * 128 + (MH)*64 + i * 16 + lr) * 32 + ce]; \
    if ((MH) == 0) {                                                                  \
      _Pragma("unroll")                                                               \
      for (int j = 0; j < 4; j++)                                                     \
        bfg[j] = *(const short8*)&lsB[slot][(wc * 64 + j * 16 + lr) * 32 + ce];       \
    }                                                                                 \
    if (st) { STG; }                                                                  \
    if ((VM) == 1) {                                                                  \
      if (st) asm volatile("s_waitcnt vmcnt(4)" ::: "memory");                        \
      else    asm volatile("s_waitcnt vmcnt(0)" ::: "memory");                        \
    } else if ((VM) == 2) {                                                           \
      if (st) asm volatile("s_waitcnt vmcnt(4)" ::: "memory");                        \
    }                                                                                 \
    __builtin_amdgcn_s_barrier();                                                     \
    __builtin_amdgcn_s_setprio(1);                                                    \
    _Pragma("unroll")                                                                 \
    for (int i = 0; i < 4; i++)                                                       \
      _Pragma("unroll")                                                               \
      for (int j = 0; j < 4; j++)                                                     \
        acc[(MH)*4 + i][j] =                                                          \
            __builtin_amdgcn_mfma_f32_16x16x32_bf16(af[i], bfg[j], acc[(MH)*4 + i][j], 0, 0, 0); \
    __builtin_amdgcn_s_setprio(0);                                                    \
    __builtin_amdgcn_s_barrier();                                                     \
  }

  for (int t = 0; t < NT; t++) {
    const int sb = (2 * t) & 3;
    const bool st = (t < NT - 1);
    const int h2 = 2 * t + 2, h3 = 2 * t + 3;
    PHASE(0, 0, stageA(h2), 0)
    PHASE(0, 1, stageB(h2), 1)
    PHASE(1, 0, stageA(h3), 0)
    PHASE(1, 1, stageB(h3), 2)
  }
#undef PHASE

  // epilogue: C/D layout col = lane&15, row = (lane>>4)*4 + reg
#pragma unroll
  for (int i = 0; i < 8; i++)
#pragma unroll
    for (int j = 0; j < 4; j++) {
      int gm = m0 + wr * 128 + i * 16 + (lane >> 4) * 4;
      int gn = n0 + wc * 64 + j * 16 + lr;
      TC* cp = C + (size_t)gm * N + gn;
#pragma unroll
      for (int r = 0; r < 4; r++) cstore(cp + (size_t)r * N, acc[i][j][r]);
    }
}

// ---------------- per-head RMSNorm + NeoX RoPE (q,k only) ----------------
__global__ void norm_rope_kernel(const unsigned short* __restrict__ qkv,
                                 const int* __restrict__ positions,
                                 const float* __restrict__ rms_w,
                                 unsigned short* __restrict__ qa,
                                 unsigned short* __restrict__ ka) {
  const int m = blockIdx.x;           // token index b*T + t
  const int b = m >> 11, tt = m & 2047;
  const int lane = threadIdx.x;       // 64 lanes; lane d owns pair (d, d+64)
  const float pos = (float)positions[m];
  const float inv_freq = powf(10000.0f, -(float)lane * (1.0f / 64.0f));
  float sv, cv;
  sincosf(pos * inv_freq, &sv, &cv);
  const float w1 = rms_w[lane], w2 = rms_w[lane + 64];
  const unsigned short* src = qkv + (size_t)m * OUTQKV;
  for (int h = 0; h < 24; h++) {      // 16 q heads + 8 k heads
    unsigned short r1 = src[h * 128 + lane], r2 = src[h * 128 + 64 + lane];
    float x1 = bf2f(r1), x2 = bf2f(r2);
    float ss = x1 * x1 + x2 * x2;
    ss += __shfl_xor(ss, 1);  ss += __shfl_xor(ss, 2);  ss += __shfl_xor(ss, 4);
    ss += __shfl_xor(ss, 8);  ss += __shfl_xor(ss, 16); ss += __shfl_xor(ss, 32);
    float rstd = rsqrtf(ss * (1.0f / 128.0f) + 1e-6f);
    float y1 = x1 * rstd * w1, y2 = x2 * rstd * w2;
    float o1 = y1 * cv - y2 * sv, o2 = y2 * cv + y1 * sv;
    unsigned short* dst;
    if (h < 16) dst = qa + (((size_t)b * NH + h) * T_SEQ + tt) * HD;
    else        dst = ka + (((size_t)b * NKV + (h - 16)) * T_SEQ + tt) * HD;
    dst[lane] = f2bf(o1); dst[lane + 64] = f2bf(o2);
  }
}

// ---------------- V transpose: qkv v-section -> vat[b][kvh][d][T] ----------------
__global__ __launch_bounds__(256) void v_transpose(const unsigned short* __restrict__ qkv,
                                                   unsigned short* __restrict__ vat) {
  __shared__ unsigned short tile[64][136];
  const int tt0 = blockIdx.x * 64;
  const int kvh = blockIdx.y, b = blockIdx.z;
  const int t = threadIdx.x;
  {
    const int tok = t >> 2, d0 = (t & 3) * 32;
    const unsigned short* src = qkv + (size_t)((size_t)b * T_SEQ + tt0 + tok) * OUTQKV
                                + QSIZE + KVSIZE + kvh * HD + d0;
#pragma unroll
    for (int i = 0; i < 4; i++)
      *(u16x8*)&tile[tok][d0 + i * 8] = *(const u16x8*)(src + i * 8);
  }
  __syncthreads();
  {
    const int d = t >> 1, c0 = (t & 1) * 32;
    unsigned short* dst = vat + ((size_t)((size_t)b * NKV + kvh) * HD + d) * T_SEQ + tt0 + c0;
#pragma unroll
    for (int j = 0; j < 4; j++) {
      u16x8 v;
#pragma unroll
      for (int e = 0; e < 8; e++) v[e] = tile[c0 + j * 8 + e][d];
      *(u16x8*)(dst + j * 8) = v;
    }
  }
}

// ---------------- flash attention (causal, GQA paired: 2 q-heads/block) ----------------
__global__ __launch_bounds__(512, 4) void attn_kernel(const unsigned short* __restrict__ qa,
                                                      const unsigned short* __restrict__ ka,
                                                      const unsigned short* __restrict__ vat,
                                                      unsigned short* __restrict__ ob) {
  __shared__ unsigned short ks[64 * 136];
  __shared__ unsigned short vt[128 * 72];
  __shared__ unsigned short ps[8][16 * 72];

  const int bx = blockIdx.x;
  const int qt = 31 - (bx >> 4);          // heavy blocks dispatched first (LPT)
  const int kvh = bx & 7, b = (bx >> 3) & 1;
  const int t = threadIdx.x, w = t >> 6, lane = t & 63;
  const int lr = lane & 15, lk = (lane >> 4) * 8, lrow = (lane >> 4) * 4;
  const int h = kvh * 2 + (w >> 2);
  const int rq = (w & 3) * 16;

  const unsigned short* Kg = ka + ((size_t)b * NKV + kvh) * T_SEQ * HD;
  const unsigned short* Vg = vat + ((size_t)b * NKV + kvh) * (size_t)HD * T_SEQ;

  const int krow = t >> 3, kd0 = (t & 7) * 16;  // K staging: 64 rows x 128 d
  const int vd = t >> 2, vk0 = (t & 3) * 16;    // V^T staging: 128 d x 64 k

  short8 qf[4];
  const unsigned short* Qg = qa + (((size_t)b * NH + h) * T_SEQ + qt * 64 + rq + lr) * HD;
#pragma unroll
  for (int kk = 0; kk < 4; kk++) qf[kk] = *(const short8*)(Qg + kk * 32 + lk);

  {
    const u16x8* kp = (const u16x8*)(Kg + (size_t)krow * HD + kd0);
    u16x8 k0v = kp[0], k1v = kp[1];
    const u16x8* vp = (const u16x8*)(Vg + (size_t)vd * T_SEQ + vk0);
    u16x8 v0v = vp[0], v1v = vp[1];
    *(u16x8*)&ks[krow * 136 + kd0] = k0v;
    *(u16x8*)&ks[krow * 136 + kd0 + 8] = k1v;
    *(u16x8*)&vt[vd * 72 + vk0] = v0v;
    *(u16x8*)&vt[vd * 72 + vk0 + 8] = v1v;
  }
  __syncthreads();

  f32x4 oacc[8] = {};
  float mrow[4] = {-1e30f, -1e30f, -1e30f, -1e30f};
  float lsum[4] = {0.f, 0.f, 0.f, 0.f};
  const float scale = 0.08838834764831845f;  // 1/sqrt(128)

  for (int j = 0; j <= qt; j++) {
    const bool more = (j < qt);
    u16x8 kr0, kr1, vr0, vr1;
    if (more) {  // T14: issue next-tile loads early; write after barrier
      const u16x8* kp = (const u16x8*)(Kg + (size_t)((j + 1) * 64 + krow) * HD + kd0);
      kr0 = kp[0]; kr1 = kp[1];
      const u16x8* vp = (const u16x8*)(Vg + (size_t)vd * T_SEQ + (j + 1) * 64 + vk0);
      vr0 = vp[0]; vr1 = vp[1];
    }
    f32x4 sacc[4] = {};
    __builtin_amdgcn_s_setprio(1);
#pragma unroll
    for (int jf = 0; jf < 4; jf++)
#pragma unroll
      for (int kk = 0; kk < 4; kk++) {
        short8 bk = *(const short8*)&ks[(jf * 16 + lr) * 136 + kk * 32 + lk];
        sacc[jf] = __builtin_amdgcn_mfma_f32_16x16x32_bf16(qf[kk], bk, sacc[jf], 0, 0, 0);
      }
    __builtin_amdgcn_s_setprio(0);
    const int rbase = qt * 64 + rq + lrow;
    const int cbase = j * 64 + lr;
#pragma unroll
    for (int r = 0; r < 4; r++) {
      float sv4[4], vmax = -1e30f;
#pragma unroll
      for (int jf = 0; jf < 4; jf++) {
        float s = sacc[jf][r] * scale;
        if (cbase + jf * 16 > rbase + r) s = -1e30f;
        sv4[jf] = s;
        vmax = fmaxf(vmax, s);
      }
      vmax = fmaxf(vmax, __shfl_xor(vmax, 1));
      vmax = fmaxf(vmax, __shfl_xor(vmax, 2));
      vmax = fmaxf(vmax, __shfl_xor(vmax, 4));
      vmax = fmaxf(vmax, __shfl_xor(vmax, 8));
      float mnew = fmaxf(mrow[r], vmax);
      float corr = __expf(mrow[r] - mnew);
      mrow[r] = mnew;
      float psum = 0.f;
#pragma unroll
      for (int jf = 0; jf < 4; jf++) {
        float p = __expf(sv4[jf] - mnew);
        psum += p;
        ps[w][(lrow + r) * 72 + jf * 16 + lr] = f2bf(p);
      }
      psum += __shfl_xor(psum, 1); psum += __shfl_xor(psum, 2);
      psum += __shfl_xor(psum, 4); psum += __shfl_xor(psum, 8);
      lsum[r] = lsum[r] * corr + psum;
#pragma unroll
      for (int dt = 0; dt < 8; dt++) oacc[dt][r] *= corr;
    }
    short8 pf0 = *(const short8*)&ps[w][lr * 72 + lk];
    short8 pf1 = *(const short8*)&ps[w][lr * 72 + 32 + lk];
    __builtin_amdgcn_s_setprio(1);
#pragma unroll
    for (int dt = 0; dt < 8; dt++) {
      short8 bv0 = *(const short8*)&vt[(dt * 16 + lr) * 72 + lk];
      short8 bv1 = *(const short8*)&vt[(dt * 16 + lr) * 72 + 32 + lk];
      oacc[dt] = __builtin_amdgcn_mfma_f32_16x16x32_bf16(pf0, bv0, oacc[dt], 0, 0, 0);
      oacc[dt] = __builtin_amdgcn_mfma_f32_16x16x32_bf16(pf1, bv1, oacc[dt], 0, 0, 0);
    }
    __builtin_amdgcn_s_setprio(0);
    __syncthreads();
    if (more) {
      *(u16x8*)&ks[krow * 136 + kd0] = kr0;
      *(u16x8*)&ks[krow * 136 + kd0 + 8] = kr1;
      *(u16x8*)&vt[vd * 72 + vk0] = vr0;
      *(u16x8*)&vt[vd * 72 + vk0 + 8] = vr1;
      __syncthreads();
    }
  }
#pragma unroll
  for (int r = 0; r < 4; r++) {
    float inv = 1.0f / lsum[r];
    int row = qt * 64 + rq + lrow + r;
    unsigned short* dst = ob + ((size_t)b * T_SEQ + row) * QSIZE + h * HD;
#pragma unroll
    for (int dt = 0; dt < 8; dt++)
      dst[dt * 16 + lr] = f2bf(oacc[dt][r] * inv);
  }
}

// ---------------- launch ----------------
extern "C" void kernel_launch(void* const* d_in, const int* in_sizes, int n_in,
                              void* d_out, int out_size, void* d_ws, size_t ws_size,
                              hipStream_t stream) {
  const int* positions = (const int*)d_in[0];
  const float* hidden  = (const float*)d_in[1];
  const float* w_qkv   = (const float*)d_in[2];
  const float* w_o     = (const float*)d_in[3];
  const float* rms_w   = (const float*)d_in[4];
  float* out = (float*)d_out;

  // R0: qkv (later ob) | R1: hb -> qa -> wob | R2: wqkvb -> ka + vat   (total ~67 MB)
  unsigned short* qkv   = (unsigned short*)d_ws;                   // [4096][4096]
  unsigned short* hb    = qkv + (size_t)M_TOK * OUTQKV;            // [4096][2048]
  unsigned short* wqkvb = hb + (size_t)M_TOK * HIDDEN;             // [4096][2048]
  unsigned short* qa    = hb;                                      // [2][16][2048][128]
  unsigned short* ka    = wqkvb;                                   // [2][8][2048][128]
  unsigned short* vat   = wqkvb + (size_t)B_SZ * NKV * T_SEQ * HD; // [2][8][128][2048]
  unsigned short* wob   = hb;                                      // [2048][2048]
  unsigned short* ob    = qkv;                                     // [4096][2048]

  cvt_f32_bf16<<<(M_TOK * HIDDEN / 8 + 255) / 256, 256, 0, stream>>>(hidden, hb, M_TOK * HIDDEN / 8);
  cvt_f32_bf16<<<(OUTQKV * HIDDEN / 8 + 255) / 256, 256, 0, stream>>>(w_qkv, wqkvb, OUTQKV * HIDDEN / 8);
  gemm8<unsigned short>
      <<<(M_TOK / 256) * (OUTQKV / 256), 512, 0, stream>>>(hb, wqkvb, qkv, M_TOK, OUTQKV, HIDDEN);
  norm_rope_kernel<<<M_TOK, 64, 0, stream>>>(qkv, positions, rms_w, qa, ka);
  v_transpose<<<dim3(T_SEQ / 64, NKV, B_SZ), 256, 0, stream>>>(qkv, vat);
  attn_kernel<<<512, 512, 0, stream>>>(qa, ka, vat, ob);
  cvt_f32_bf16<<<(HIDDEN * QSIZE / 8 + 255) / 256, 256, 0, stream>>>(w_o, wob, HIDDEN * QSIZE / 8);
  gemm8<float>
      <<<(M_TOK / 256) * (HIDDEN / 256), 512, 0, stream>>>(ob, wob, out, M_TOK, HIDDEN, QSIZE);
}

// Round 4
// 212.981 us; speedup vs baseline: 2.2913x; 1.3342x over previous
//
#include <hip/hip_runtime.h>
#include <hip/hip_bf16.h>

typedef __attribute__((ext_vector_type(8))) short short8;
typedef __attribute__((ext_vector_type(8))) unsigned short u16x8;
typedef __attribute__((ext_vector_type(4))) float f32x4;
typedef __attribute__((ext_vector_type(16))) float f32x16;

#define HIDDEN 2048
#define NH 16
#define NKV 8
#define HD 128
#define T_SEQ 2048
#define B_SZ 2
#define M_TOK (B_SZ * T_SEQ)         // 4096
#define QSIZE (NH * HD)              // 2048
#define KVSIZE (NKV * HD)            // 1024
#define OUTQKV (QSIZE + 2 * KVSIZE)  // 4096

__device__ __forceinline__ unsigned short f2bf(float f) {
  unsigned int u = __builtin_bit_cast(unsigned int, f);
  u += 0x7FFFu + ((u >> 16) & 1u);   // round-to-nearest-even
  return (unsigned short)(u >> 16);
}
__device__ __forceinline__ float bf2f(unsigned short h) {
  return __builtin_bit_cast(float, (unsigned int)h << 16);
}

typedef __attribute__((address_space(3))) void lds_void;
typedef __attribute__((address_space(1))) const void glb_void;
__device__ __forceinline__ void gld16(const void* g, void* l) {
  __builtin_amdgcn_global_load_lds((glb_void*)g, (lds_void*)l, 16, 0, 0);
}

__device__ __forceinline__ void cstore(float* p, float v) { *p = v; }
__device__ __forceinline__ void cstore(unsigned short* p, float v) { *p = f2bf(v); }

__device__ __forceinline__ float exp2fast(float x) {
  float r;
  asm("v_exp_f32 %0, %1" : "=v"(r) : "v"(x));
  return r;
}
__device__ __forceinline__ unsigned cvtpk(float lo, float hi) {
  unsigned r;
  asm("v_cvt_pk_bf16_f32 %0, %1, %2" : "=v"(r) : "v"(lo), "v"(hi));
  return r;
}
__device__ __forceinline__ void pl32swap(unsigned& a, unsigned& b) {
  // a.hi_lanes <-> b.lo_lanes: a' = {l<32: a, l>=32: b[l-32]}, b' = {l<32: a[l+32], l>=32: b}
  asm volatile("v_permlane32_swap_b32 %0, %1" : "+v"(a), "+v"(b));
}

template <int N>
__device__ __forceinline__ void vwait();
template <> __device__ __forceinline__ void vwait<0>() { asm volatile("s_waitcnt vmcnt(0)" ::: "memory"); }
template <> __device__ __forceinline__ void vwait<3>() { asm volatile("s_waitcnt vmcnt(3)" ::: "memory"); }
template <> __device__ __forceinline__ void vwait<4>() { asm volatile("s_waitcnt vmcnt(4)" ::: "memory"); }

// ---------------- f32 -> bf16 convert ----------------
__global__ void cvt_f32_bf16(const float* __restrict__ in, unsigned short* __restrict__ out, int n8) {
  int i = blockIdx.x * blockDim.x + threadIdx.x;
  if (i >= n8) return;
  const float4* p = (const float4*)in + (size_t)i * 2;
  float4 a = p[0], b = p[1];
  u16x8 o = {f2bf(a.x), f2bf(a.y), f2bf(a.z), f2bf(a.w),
             f2bf(b.x), f2bf(b.y), f2bf(b.z), f2bf(b.w)};
  ((u16x8*)out)[i] = o;
}

// ---------------- BMx256 8-phase GEMM: C[M,N] = A[M,K] x B[N,K]^T (bf16 in) ----------------
// MT = M-tiles (16 rows each) per wave; BM = MT*32 (256 or 128). BN = 256.
template <int MT, typename TC>
__global__ __launch_bounds__(512, 2) void gemm8(const unsigned short* __restrict__ A,
                                                const unsigned short* __restrict__ B,
                                                TC* __restrict__ C,
                                                int M, int N, int K) {
  constexpr int BM = MT * 32;
  constexpr int MT2 = MT / 2;
  constexpr int VMN = (MT == 8) ? 4 : 3;
  __shared__ unsigned short lsA[4][BM * 32];
  __shared__ unsigned short lsB[4][8192];
  const int tid = threadIdx.x;
  const int wave = tid >> 6, lane = tid & 63;
  const int wr = wave >> 2, wc = wave & 3;       // 2 x 4 waves
  const int lr = lane & 15;
  const int ntn = N >> 8;
  const int cpx = gridDim.x >> 3;                // bijective XCD swizzle (grid % 8 == 0)
  const int wg = (blockIdx.x & 7) * cpx + (blockIdx.x >> 3);
  const int m0 = (wg / ntn) * BM, n0 = (wg % ntn) * 256;
  const int ce = 8 * ((lane >> 4) ^ ((lr >> 1) & 3));
  const int rr0 = tid >> 2;
  const int cle = 8 * ((tid & 3) ^ ((rr0 >> 1) & 3));
  const unsigned short* pA0 = A + (size_t)(m0 + rr0) * K + cle;
  const unsigned short* pA1 = pA0 + (size_t)128 * K;
  const unsigned short* pB0 = B + (size_t)(n0 + rr0) * K + cle;
  const unsigned short* pB1 = pB0 + (size_t)128 * K;
  const int dst0 = 8 * tid, dst1 = 4096 + 8 * tid;

  auto stageA = [&](int hn) {
    const int s = hn & 3;
    gld16(pA0 + hn * 32, &lsA[s][dst0]);
    if constexpr (MT == 8) gld16(pA1 + hn * 32, &lsA[s][dst1]);
  };
  auto stageB = [&](int hn) {
    const int s = hn & 3;
    gld16(pB0 + hn * 32, &lsB[s][dst0]);
    gld16(pB1 + hn * 32, &lsB[s][dst1]);
  };

  f32x4 acc[MT][4] = {};
  short8 af[MT2], bfg[4];
  const int NT = K >> 6;

  stageA(0); stageB(0); stageA(1); stageB(1);
  vwait<0>();
  __syncthreads();

#define PHASE(KK, MH, STG, VM)                                                            \
  {                                                                                       \
    const int slot = sb + (KK);                                                           \
    _Pragma("unroll")                                                                     \
    for (int i = 0; i < MT2; i++)                                                         \
      af[i] = *(const short8*)&lsA[slot][(wr * (MT * 16) + (MH) * (MT * 8) + i * 16 + lr) * 32 + ce]; \
    if ((MH) == 0) {                                                                      \
      _Pragma("unroll")                                                                   \
      for (int j = 0; j < 4; j++)                                                         \
        bfg[j] = *(const short8*)&lsB[slot][(wc * 64 + j * 16 + lr) * 32 + ce];           \
    }                                                                                     \
    if (st) { STG; }                                                                      \
    if ((VM) == 1) {                                                                      \
      if (st) vwait<VMN>(); else vwait<0>();                                              \
    } else if ((VM) == 2) {                                                               \
      if (st) vwait<VMN>();                                                               \
    }                                                                                     \
    __builtin_amdgcn_s_barrier();                                                         \
    __builtin_amdgcn_s_setprio(1);                                                        \
    _Pragma("unroll")                                                                     \
    for (int i = 0; i < MT2; i++)                                                         \
      _Pragma("unroll")                                                                   \
      for (int j = 0; j < 4; j++)                                                         \
        acc[(MH)*MT2 + i][j] =                                                            \
            __builtin_amdgcn_mfma_f32_16x16x32_bf16(af[i], bfg[j], acc[(MH)*MT2 + i][j], 0, 0, 0); \
    __builtin_amdgcn_s_setprio(0);                                                        \
    __builtin_amdgcn_s_barrier();                                                         \
  }

  for (int t = 0; t < NT; t++) {
    const int sb = (2 * t) & 3;
    const bool st = (t < NT - 1);
    const int h2 = 2 * t + 2, h3 = 2 * t + 3;
    PHASE(0, 0, stageA(h2), 0)
    PHASE(0, 1, stageB(h2), 1)
    PHASE(1, 0, stageA(h3), 0)
    PHASE(1, 1, stageB(h3), 2)
  }
#undef PHASE

#pragma unroll
  for (int i = 0; i < MT; i++)
#pragma unroll
    for (int j = 0; j < 4; j++) {
      int gm = m0 + wr * (MT * 16) + i * 16 + (lane >> 4) * 4;
      int gn = n0 + wc * 64 + j * 16 + lr;
      TC* cp = C + (size_t)gm * N + gn;
#pragma unroll
      for (int r = 0; r < 4; r++) cstore(cp + (size_t)r * N, acc[i][j][r]);
    }
}

// ---------------- per-head RMSNorm + NeoX RoPE (q,k only) ----------------
__global__ void norm_rope_kernel(const unsigned short* __restrict__ qkv,
                                 const int* __restrict__ positions,
                                 const float* __restrict__ rms_w,
                                 unsigned short* __restrict__ qa,
                                 unsigned short* __restrict__ ka) {
  const int m = blockIdx.x;
  const int b = m >> 11, tt = m & 2047;
  const int lane = threadIdx.x;
  const float pos = (float)positions[m];
  const float inv_freq = powf(10000.0f, -(float)lane * (1.0f / 64.0f));
  float sv, cv;
  sincosf(pos * inv_freq, &sv, &cv);
  const float w1 = rms_w[lane], w2 = rms_w[lane + 64];
  const unsigned short* src = qkv + (size_t)m * OUTQKV;
  for (int h = 0; h < 24; h++) {
    unsigned short r1 = src[h * 128 + lane], r2 = src[h * 128 + 64 + lane];
    float x1 = bf2f(r1), x2 = bf2f(r2);
    float ss = x1 * x1 + x2 * x2;
    ss += __shfl_xor(ss, 1);  ss += __shfl_xor(ss, 2);  ss += __shfl_xor(ss, 4);
    ss += __shfl_xor(ss, 8);  ss += __shfl_xor(ss, 16); ss += __shfl_xor(ss, 32);
    float rstd = rsqrtf(ss * (1.0f / 128.0f) + 1e-6f);
    float y1 = x1 * rstd * w1, y2 = x2 * rstd * w2;
    float o1 = y1 * cv - y2 * sv, o2 = y2 * cv + y1 * sv;
    unsigned short* dst;
    if (h < 16) dst = qa + (((size_t)b * NH + h) * T_SEQ + tt) * HD;
    else        dst = ka + (((size_t)b * NKV + (h - 16)) * T_SEQ + tt) * HD;
    dst[lane] = f2bf(o1); dst[lane + 64] = f2bf(o2);
  }
}

// ---------------- V transpose: qkv v-section -> vat[b][kvh][d][T] ----------------
__global__ __launch_bounds__(256) void v_transpose(const unsigned short* __restrict__ qkv,
                                                   unsigned short* __restrict__ vat) {
  __shared__ unsigned short tile[64][136];
  const int tt0 = blockIdx.x * 64;
  const int kvh = blockIdx.y, b = blockIdx.z;
  const int t = threadIdx.x;
  {
    const int tok = t >> 2, d0 = (t & 3) * 32;
    const unsigned short* src = qkv + (size_t)((size_t)b * T_SEQ + tt0 + tok) * OUTQKV
                                + QSIZE + KVSIZE + kvh * HD + d0;
#pragma unroll
    for (int i = 0; i < 4; i++)
      *(u16x8*)&tile[tok][d0 + i * 8] = *(const u16x8*)(src + i * 8);
  }
  __syncthreads();
  {
    const int d = t >> 1, c0 = (t & 1) * 32;
    unsigned short* dst = vat + ((size_t)((size_t)b * NKV + kvh) * HD + d) * T_SEQ + tt0 + c0;
#pragma unroll
    for (int j = 0; j < 4; j++) {
      u16x8 v;
#pragma unroll
      for (int e = 0; e < 8; e++) v[e] = tile[c0 + j * 8 + e][d];
      *(u16x8*)(dst + j * 8) = v;
    }
  }
}

// ---------------- flash attention: 32x32 MFMA, swapped operands, in-reg softmax ----------------
// block = 256 thr = 4 waves; wave w: head kvh*2 + (w>>1), q-rows qt*64 + (w&1)*32 + (lane&31).
// S^T = mfma(K, Q): lane holds S[kv = t*32 + (r&3)+8(r>>2)+4h5][q = lane&31] for tiles t=0,1.
// O^T = mfma(V^T, P^T): P^T B-frags built in-register via cvt_pk + permlane32_swap.
__global__ __launch_bounds__(256, 2) void attn_kernel(const unsigned short* __restrict__ qa,
                                                      const unsigned short* __restrict__ ka,
                                                      const unsigned short* __restrict__ vat,
                                                      unsigned short* __restrict__ ob) {
  __shared__ unsigned short ks[2][64 * 128];
  __shared__ unsigned short vs[2][128 * 64];
  const int bx = blockIdx.x;
  const int qt = 31 - (bx >> 4);          // LPT: heavy first
  const int kvh = bx & 7, b = (bx >> 3) & 1;
  const int tid = threadIdx.x, w = tid >> 6, lane = tid & 63;
  const int l31 = lane & 31, h5 = lane >> 5;
  const int h = kvh * 2 + (w >> 1);
  const int qrow = qt * 64 + (w & 1) * 32 + l31;   // absolute q token in sequence
  const float cexp = 0.08838834764831845f * 1.44269504088896340f;  // scale * log2(e)

  const unsigned short* Kg = ka + ((size_t)b * NKV + kvh) * T_SEQ * HD;
  const unsigned short* Vg = vat + ((size_t)b * NKV + kvh) * (size_t)HD * T_SEQ;

  short8 qf[8];  // B-frag: Q[qrow][c*16 + h5*8 + e]
  {
    const unsigned short* Qg = qa + (((size_t)b * NH + h) * T_SEQ + qrow) * HD;
#pragma unroll
    for (int c = 0; c < 8; c++) qf[c] = *(const short8*)(Qg + c * 16 + h5 * 8);
  }

  // staging (XOR-swizzled source, linear LDS dest):
  // K granule g: row g>>4 (64 rows x 16 gran), src col elem 8*((g&15)^(row&15))
  // V granule g: row d g>>3 (128 rows x 8 gran), src col elem 8*((g&7)^(d&7))
  auto stage = [&](int j, int buf) {
#pragma unroll
    for (int s = 0; s < 4; s++) {
      int g = s * 256 + tid;
      int kr = g >> 4;
      int kc = 8 * ((g & 15) ^ (kr & 15));
      gld16(Kg + (size_t)(j * 64 + kr) * HD + kc, &ks[buf][g * 8]);
    }
#pragma unroll
    for (int s = 0; s < 4; s++) {
      int g = s * 256 + tid;
      int vd = g >> 3;
      int vc = 8 * ((g & 7) ^ (vd & 7));
      gld16(Vg + (size_t)vd * T_SEQ + j * 64 + vc, &vs[buf][g * 8]);
    }
  };

  stage(0, 0);
  vwait<0>();
  __syncthreads();

  f32x16 oacc[4] = {};
  float mraw = -1e30f, m2 = -3.0e29f, lsum = 0.f;

  for (int j = 0; j <= qt; j++) {
    const int buf = j & 1;
    if (j < qt) stage(j + 1, buf ^ 1);  // T14: issue early, lands before end-of-iter vmcnt(0)

    // S^T = K . Q^T
    f32x16 sacc[2] = {};
    __builtin_amdgcn_s_setprio(1);
#pragma unroll
    for (int c = 0; c < 8; c++) {
#pragma unroll
      for (int t = 0; t < 2; t++) {
        const int row = t * 32 + l31;
        short8 kf = *(const short8*)&ks[buf][row * 128 + ((c * 16 + h5 * 8) ^ (8 * (l31 & 15)))];
        sacc[t] = __builtin_amdgcn_mfma_f32_32x32x16_bf16(kf, qf[c], sacc[t], 0, 0, 0);
      }
    }
    __builtin_amdgcn_s_setprio(0);

    // causal mask (active only near diagonal; wave-uniform branch)
    if (j * 64 + 63 > qt * 64 + (w & 1) * 32) {
#pragma unroll
      for (int t = 0; t < 2; t++)
#pragma unroll
        for (int r = 0; r < 16; r++) {
          int kvg = j * 64 + t * 32 + (r & 3) + 8 * (r >> 2) + 4 * h5;
          if (kvg > qrow) sacc[t][r] = -1e30f;
        }
    }
    // row max: in-reg over 32 vals + 1 swap with partner lane (l^32 holds other half of row)
    float mx = sacc[0][0];
#pragma unroll
    for (int t = 0; t < 2; t++)
#pragma unroll
      for (int r = 0; r < 16; r++) mx = fmaxf(mx, sacc[t][r]);
    mx = fmaxf(mx, __shfl_xor(mx, 32));
    if (__any((mx - mraw) * cexp > 11.5f)) {  // T13 defer-max (bound P <= 2^11.5)
      float mn = fmaxf(mraw, mx);
      float corr = exp2fast((mraw - mn) * cexp);
      mraw = mn;
      m2 = mn * cexp;
      lsum *= corr;
#pragma unroll
      for (int dt = 0; dt < 4; dt++)
#pragma unroll
        for (int r = 0; r < 16; r++) oacc[dt][r] *= corr;
    }
    // P = exp2(s*cexp - m2); build PV B-frags: frag[kt] elem e <-> kv = kt*16 + 8*h5 + e
    short8 pf[4];
#pragma unroll
    for (int kt = 0; kt < 4; kt++) {
      const int t = kt >> 1, r0 = (kt & 1) * 8;
      float e0 = exp2fast(sacc[t][r0 + 0] * cexp - m2);
      float e1 = exp2fast(sacc[t][r0 + 1] * cexp - m2);
      float e2 = exp2fast(sacc[t][r0 + 2] * cexp - m2);
      float e3 = exp2fast(sacc[t][r0 + 3] * cexp - m2);
      float e4 = exp2fast(sacc[t][r0 + 4] * cexp - m2);
      float e5 = exp2fast(sacc[t][r0 + 5] * cexp - m2);
      float e6 = exp2fast(sacc[t][r0 + 6] * cexp - m2);
      float e7 = exp2fast(sacc[t][r0 + 7] * cexp - m2);
      lsum += ((e0 + e1) + (e2 + e3)) + ((e4 + e5) + (e6 + e7));
      unsigned a0 = cvtpk(e0, e1), a1 = cvtpk(e2, e3);
      unsigned b0 = cvtpk(e4, e5), b1 = cvtpk(e6, e7);
      pl32swap(a0, b0);
      pl32swap(a1, b1);
      uint4 uu = make_uint4(a0, a1, b0, b1);
      pf[kt] = __builtin_bit_cast(short8, uu);
    }
    // O^T += V^T . P^T
    __builtin_amdgcn_s_setprio(1);
#pragma unroll
    for (int dt = 0; dt < 4; dt++) {
      const int d = dt * 32 + l31;
#pragma unroll
      for (int kt = 0; kt < 4; kt++) {
        short8 vf = *(const short8*)&vs[buf][d * 64 + ((kt * 16 + h5 * 8) ^ (8 * (l31 & 7)))];
        oacc[dt] = __builtin_amdgcn_mfma_f32_32x32x16_bf16(vf, pf[kt], oacc[dt], 0, 0, 0);
      }
    }
    __builtin_amdgcn_s_setprio(0);
    vwait<0>();        // next tile landed
    __syncthreads();   // all waves done reading current buf
  }

  lsum += __shfl_xor(lsum, 32);
  const float inv = 1.0f / lsum;
  unsigned short* dst = ob + ((size_t)b * T_SEQ + qrow) * QSIZE + h * HD;
#pragma unroll
  for (int dt = 0; dt < 4; dt++)
#pragma unroll
    for (int rg = 0; rg < 4; rg++) {
      ushort4 v4;
      v4.x = f2bf(oacc[dt][rg * 4 + 0] * inv);
      v4.y = f2bf(oacc[dt][rg * 4 + 1] * inv);
      v4.z = f2bf(oacc[dt][rg * 4 + 2] * inv);
      v4.w = f2bf(oacc[dt][rg * 4 + 3] * inv);
      *(ushort4*)(dst + dt * 32 + rg * 8 + 4 * h5) = v4;
    }
}

// ---------------- launch ----------------
extern "C" void kernel_launch(void* const* d_in, const int* in_sizes, int n_in,
                              void* d_out, int out_size, void* d_ws, size_t ws_size,
                              hipStream_t stream) {
  const int* positions = (const int*)d_in[0];
  const float* hidden  = (const float*)d_in[1];
  const float* w_qkv   = (const float*)d_in[2];
  const float* w_o     = (const float*)d_in[3];
  const float* rms_w   = (const float*)d_in[4];
  float* out = (float*)d_out;

  unsigned short* qkv   = (unsigned short*)d_ws;                   // [4096][4096]
  unsigned short* hb    = qkv + (size_t)M_TOK * OUTQKV;            // [4096][2048]
  unsigned short* wqkvb = hb + (size_t)M_TOK * HIDDEN;             // [4096][2048]
  unsigned short* qa    = hb;                                      // alias after gemm1
  unsigned short* ka    = wqkvb;                                   // alias after gemm1
  unsigned short* vat   = wqkvb + (size_t)B_SZ * NKV * T_SEQ * HD;
  unsigned short* wob   = hb;                                      // alias after attn
  unsigned short* ob    = qkv;                                     // alias after v_transpose

  cvt_f32_bf16<<<(M_TOK * HIDDEN / 8 + 255) / 256, 256, 0, stream>>>(hidden, hb, M_TOK * HIDDEN / 8);
  cvt_f32_bf16<<<(OUTQKV * HIDDEN / 8 + 255) / 256, 256, 0, stream>>>(w_qkv, wqkvb, OUTQKV * HIDDEN / 8);
  gemm8<8, unsigned short>
      <<<(M_TOK / 256) * (OUTQKV / 256), 512, 0, stream>>>(hb, wqkvb, qkv, M_TOK, OUTQKV, HIDDEN);
  norm_rope_kernel<<<M_TOK, 64, 0, stream>>>(qkv, positions, rms_w, qa, ka);
  v_transpose<<<dim3(T_SEQ / 64, NKV, B_SZ), 256, 0, stream>>>(qkv, vat);
  attn_kernel<<<512, 256, 0, stream>>>(qa, ka, vat, ob);
  cvt_f32_bf16<<<(HIDDEN * QSIZE / 8 + 255) / 256, 256, 0, stream>>>(w_o, wob, HIDDEN * QSIZE / 8);
  gemm8<4, float>
      <<<(M_TOK / 128) * (HIDDEN / 256), 512, 0, stream>>>(ob, wob, out, M_TOK, HIDDEN, QSIZE);
}